// Round 14
// baseline (128.098 us; speedup 1.0000x reference)
//
#include <hip/hip_runtime.h>
#include <hip/hip_bf16.h>

// ---- types ----
typedef short bf16x8 __attribute__((ext_vector_type(8)));    // MFMA A/B frag (8 bf16)
typedef float floatx4 __attribute__((ext_vector_type(4)));   // 16x16 MFMA C/D frag
typedef float floatx16 __attribute__((ext_vector_type(16))); // 32x32 MFMA C/D frag
typedef unsigned uintx4 __attribute__((ext_vector_type(4)));

typedef const __attribute__((address_space(1))) void gvoid_t;
typedef __attribute__((address_space(3))) void lvoid_t;

__device__ __forceinline__ void gload_lds16(const void* g, void* l) {
  // wave-uniform LDS base; HW writes 16B at l + lane*16 per lane
  __builtin_amdgcn_global_load_lds((gvoid_t*)g, (lvoid_t*)l, 16, 0, 0);
}

__device__ __forceinline__ unsigned short f2bf(float f) {
  union { float f; unsigned u; } c; c.f = f;
  unsigned u = c.u + 0x7FFFu + ((c.u >> 16) & 1u);  // RNE
  return (unsigned short)(u >> 16);
}

#define LOG2E 1.44269504f
#define EXP2(x) __builtin_amdgcn_exp2f(x)   // raw v_exp_f32 (inputs bounded)

// lane^32 combine on the VALU: v_permlane32_swap swaps vdst[32:63] <-> vsrc[0:31];
// after the swap, {a,b} = {own,partner} pairwise in both halves for commutative
// ops.  The asm v_mov forces b into a distinct register (round-5 lesson:
// same-value "+v","+v" operands got coalesced into a self-swap).
__device__ __forceinline__ float xmax32(float x) {
  float a = x, b;
  asm("v_mov_b32 %0, %1" : "=v"(b) : "v"(x));
  asm("v_permlane32_swap_b32 %0, %1" : "+v"(a), "+v"(b));
  return fmaxf(a, b);
}
__device__ __forceinline__ float xadd32(float x) {
  float a = x, b;
  asm("v_mov_b32 %0, %1" : "=v"(b) : "v"(x));
  asm("v_permlane32_swap_b32 %0, %1" : "+v"(a), "+v"(b));
  return a + b;
}

// ================= cast kernels =================
__global__ __launch_bounds__(256) void cast_f32_bf16(const float* __restrict__ in,
                                                     unsigned short* __restrict__ out, int n4) {
  int i = blockIdx.x * blockDim.x + threadIdx.x;
  if (i >= n4) return;
  float4 v = ((const float4*)in)[i];
  ushort4 o;
  o.x = f2bf(v.x); o.y = f2bf(v.y); o.z = f2bf(v.z); o.w = f2bf(v.w);
  ((ushort4*)out)[i] = o;
}

// out[n*K + k] = in[k*N + n]
__global__ __launch_bounds__(256) void tcast_f32_bf16(const float* __restrict__ in,
                                                      unsigned short* __restrict__ out,
                                                      int K, int N) {
  int idx = blockIdx.x * blockDim.x + threadIdx.x;
  if (idx >= K * N) return;
  int k = idx / N, n = idx - k * N;
  out[n * K + k] = f2bf(in[idx]);
}

// btT[h][idx] = btab[idx][h] * log2(e)   (fold exp2 domain into the table)
__global__ __launch_bounds__(256) void tbias_kernel(const float* __restrict__ btab,
                                                    float* __restrict__ btT) {
  int i = blockIdx.x * blockDim.x + threadIdx.x;
  if (i >= 2047 * 8) return;
  int idx = i >> 3, h = i & 7;
  btT[h * 2047 + idx] = btab[i] * LOG2E;
}

// ================= GEMM: C[m][n] = sum_k A[m][k] * Bt[n][k] =================
// 128x128 tile, BK=64, 4 waves (2x2 of 64x64), mfma 16x16x32 bf16.
// (256,3): grid 768 (gemm0) / 256 (gemm1) fully co-resident at 3 blocks/CU --
// at (256,2) gemm0 ran 1.5 dispatch rounds (33% tail).  XCD-bijective block
// swizzle keeps each XCD's A/B panels L2-local (grid % 8 == 0 for both).
template <int EPI>
__global__ __launch_bounds__(256, 3) void gemm_bf16(
    const unsigned short* __restrict__ A,   // [M][K] bf16
    const unsigned short* __restrict__ Bt,  // [N][K] bf16
    int M, int N, int K,
    unsigned short* __restrict__ qo, unsigned short* __restrict__ ko,
    unsigned short* __restrict__ vo,
    float* __restrict__ out, const float* __restrict__ bias) {
  __shared__ alignas(16) unsigned short lA[128 * 64];
  __shared__ alignas(16) unsigned short lB[128 * 64];
  const int tid = threadIdx.x;
  const int wave = tid >> 6, lane = tid & 63;
  const int wr = wave >> 1, wc = wave & 1;
  const int lrow = lane & 15, lk = lane >> 4;
  // XCD-bijective swizzle over the flattened grid (gx*gy % 8 == 0)
  const int total = gridDim.x * gridDim.y;
  const int flat = blockIdx.y * gridDim.x + blockIdx.x;
  const int chunk = total >> 3;
  const int lid = (flat & 7) * chunk + (flat >> 3);
  const int m0 = (lid % gridDim.x) * 128, n0 = (lid / gridDim.x) * 128;

  floatx4 acc[4][4] = {};

  for (int k0 = 0; k0 < K; k0 += 64) {
    __syncthreads();
#pragma unroll
    for (int i = 0; i < 4; ++i) {
      int c = i * 256 + tid;        // chunk id 0..1023 (16B chunks)
      int row = c >> 3, kc = c & 7;
      int ksw = (kc ^ (row & 7)) << 3;  // pre-swizzled source (elements)
      gload_lds16(A + (size_t)(m0 + row) * K + k0 + ksw,
                  &lA[(i * 256 + wave * 64) * 8]);
      gload_lds16(Bt + (size_t)(n0 + row) * K + k0 + ksw,
                  &lB[(i * 256 + wave * 64) * 8]);
    }
    __syncthreads();
#pragma unroll
    for (int f = 0; f < 2; ++f) {
      bf16x8 av[4], bv[4];
      int kc = lk + f * 4;
#pragma unroll
      for (int mt = 0; mt < 4; ++mt) {
        int r = wr * 64 + mt * 16 + lrow;
        av[mt] = *(const bf16x8*)&lA[r * 64 + ((kc ^ (r & 7)) << 3)];
      }
#pragma unroll
      for (int nt = 0; nt < 4; ++nt) {
        int r = wc * 64 + nt * 16 + lrow;
        bv[nt] = *(const bf16x8*)&lB[r * 64 + ((kc ^ (r & 7)) << 3)];
      }
      __builtin_amdgcn_s_setprio(1);
#pragma unroll
      for (int mt = 0; mt < 4; ++mt)
#pragma unroll
        for (int nt = 0; nt < 4; ++nt)
          acc[mt][nt] = __builtin_amdgcn_mfma_f32_16x16x32_bf16(av[mt], bv[nt], acc[mt][nt], 0, 0, 0);
      __builtin_amdgcn_s_setprio(0);
    }
  }

#pragma unroll
  for (int mt = 0; mt < 4; ++mt)
#pragma unroll
    for (int nt = 0; nt < 4; ++nt)
#pragma unroll
      for (int rg = 0; rg < 4; ++rg) {
        int m = m0 + wr * 64 + mt * 16 + lk * 4 + rg;
        int n = n0 + wc * 64 + nt * 16 + lrow;
        float v = acc[mt][nt][rg];
        if constexpr (EPI == 0) {
          int b = m >> 10, ii = m & 1023;
          int sect = n >> 9, r = n & 511;
          int h = r >> 6, d = r & 63;
          size_t bh = (size_t)((b << 3) + h);
          if (sect == 0)      qo[bh * 65536 + (size_t)ii * 64 + d] = f2bf(v * (0.125f * LOG2E));
          else if (sect == 1) ko[bh * 65536 + (size_t)ii * 64 + d] = f2bf(v);
          else                vo[bh * 65536 + (size_t)d * 1024 + ii] = f2bf(v);
        } else {
          out[(size_t)m * N + n] = v + bias[n];
        }
      }
}

// ================= flash attention, 32x32 MFMA, in-block KV-split ===========
// Round-10 proven structure: K LDS-staged double-buffer, V direct-early from
// L2, (256,3) no-spill budget, per-lane softmax, permlane P-routing, raw
// v_exp_f32.  This round: s_setprio around MFMA clusters (T5, +4-7% attn).
__global__ __launch_bounds__(256, 3) void attn_kernel(
    const unsigned short* __restrict__ q,    // [64][1024][64] bf16, pre-scaled 0.125*log2e
    const unsigned short* __restrict__ kbuf, // [64][1024][64] bf16
    const unsigned short* __restrict__ vT,   // [64][64][1024] bf16
    const float* __restrict__ btT,           // [8][2047] f32, pre-scaled log2e
    unsigned short* __restrict__ ao)         // [8][1024][512] bf16
{
  __shared__ alignas(16) unsigned short lK[2][2][64 * 64];  // [pair][dbuf]
  __shared__ float lbias[1088];
  const int tid = threadIdx.x, wave = tid >> 6, lane = tid & 63;
  const int il = lane & 31, hi = lane >> 5;
  const int pr = wave >> 1;                // KV half
  const int wq = wave & 1;                 // q-row half
  // XCD-bijective swizzle: all 16 q-tiles of 8 bh land on one XCD's L2
  const int lid = ((blockIdx.x & 7) << 7) | (blockIdx.x >> 3);
  const int bh = lid >> 4, qt = lid & 15;
  const int h = bh & 7, b = bh >> 3;
  const int qB = qt * 64;
  const int i_ = qB + wq * 32 + il;        // this lane's q-row
  const size_t base = (size_t)bh * 65536;
  const unsigned short* vrow = vT + base;  // [64][1024]

  // stage bias window [qB, qB+1086] -> lbias
  for (int t = tid; t < 1087; t += 256)
    lbias[t] = btT[h * 2047 + qB + t];

  // Q frags (B-operand): Q[i_][kd*16 + hi*8 + e]
  bf16x8 qf[4];
#pragma unroll
  for (int kd = 0; kd < 4; ++kd)
    qf[kd] = *(const bf16x8*)(q + base + (size_t)i_ * 64 + kd * 16 + hi * 8);

  // pair-local staging: 2 waves cover one 64x64 K tile (4 instrs/wave)
#define STAGE_K(dst, jbase)                                                     \
  {                                                                             \
    _Pragma("unroll") for (int i = 0; i < 4; ++i) {                             \
      int c = i * 128 + wq * 64 + lane;                                         \
      int row = c >> 3, kc = c & 7;                                             \
      gload_lds16(kbuf + base + (size_t)((jbase) + row) * 64 + ((kc ^ (row & 7)) << 3), \
                  &(dst)[(i * 128 + wq * 64) * 8]);                             \
    }                                                                           \
  }

  STAGE_K(lK[pr][0], pr * 512);
  __syncthreads();

  floatx16 accA = {}, accB = {};   // O^T[d][i], db = 0 / 1 (unnormalized U)
  float m_ = -1e30f, s_ = 0.f;
  const int bias_off = (i_ - qB) + 1023 - 4 * hi;
  int buf = 0;

  for (int t = 0; t < 8; ++t) {
    const int j0 = pr * 512 + t * 64;
    if (t < 7) STAGE_K(lK[pr][buf ^ 1], j0 + 64);

    // V A-frags direct from global (L2-resident), issued EARLY so the QK^T /
    // softmax phase hides their latency: VT[db*32+il][j0 + ks*16 + hi*8 ..]
    bf16x8 vf0[4], vf1[4];
#pragma unroll
    for (int ks = 0; ks < 4; ++ks) {
      vf0[ks] = *(const bf16x8*)(vrow + (size_t)il * 1024 + j0 + ks * 16 + hi * 8);
      vf1[ks] = *(const bf16x8*)(vrow + (size_t)(32 + il) * 1024 + j0 + ks * 16 + hi * 8);
    }

    // QK^T (swapped): st = mfma(K-frag, Q-frag)
    floatx16 st0 = {}, st1 = {};
    __builtin_amdgcn_s_setprio(1);
#pragma unroll
    for (int kd = 0; kd < 4; ++kd) {
      const int kc = ((kd * 2 + hi) ^ (il & 7)) << 3;
      bf16x8 kf0 = *(const bf16x8*)&lK[pr][buf][il * 64 + kc];
      bf16x8 kf1 = *(const bf16x8*)&lK[pr][buf][(32 + il) * 64 + kc];
      st0 = __builtin_amdgcn_mfma_f32_32x32x16_bf16(kf0, qf[kd], st0, 0, 0, 0);
      st1 = __builtin_amdgcn_mfma_f32_32x32x16_bf16(kf1, qf[kd], st1, 0, 0, 0);
    }
    __builtin_amdgcn_s_setprio(0);

    // + relative bias (LDS); max via 4 independent partial chains
    const int bb = bias_off - j0;
    float pmp[4] = { -1e30f, -1e30f, -1e30f, -1e30f };
#pragma unroll
    for (int r = 0; r < 16; ++r) {
      const int jl = (r & 3) + 8 * (r >> 2);
      st0[r] += lbias[bb - jl];
      st1[r] += lbias[bb - 32 - jl];
      pmp[r & 3] = fmaxf(pmp[r & 3], fmaxf(st0[r], st1[r]));
    }
    float pm = fmaxf(fmaxf(pmp[0], pmp[1]), fmaxf(pmp[2], pmp[3]));
    // full-row max across lane^32 — pure VALU
    pm = xmax32(pm);
    // defer-max (T13): only rescale when max grew by >8 (P bounded by 2^8)
    if (!__all(pm - m_ <= 8.f)) {
      const float nm = fmaxf(m_, pm);
      const float fs = EXP2(m_ - nm);
      s_ *= fs; accA *= fs; accB *= fs;
      m_ = nm;
    }
    // P = exp2(st - m); row-sum via 4 partial accumulators
    float rsp[4] = { 0.f, 0.f, 0.f, 0.f };
#pragma unroll
    for (int r = 0; r < 16; ++r) {
      float e0 = EXP2(st0[r] - m_);
      float e1 = EXP2(st1[r] - m_);
      st0[r] = e0; st1[r] = e1;
      rsp[r & 3] += e0 + e1;
    }
    float rs = (rsp[0] + rsp[1]) + (rsp[2] + rsp[3]);
    s_ += xadd32(rs);   // own + partner halves — pure VALU

    // pack P to bf16 pairs: pk[sb][g][e2] = {lo: bf(st[4g+2e2]), hi: bf(st[4g+2e2+1])}
    unsigned pk[2][4][2];
#pragma unroll
    for (int g = 0; g < 4; ++g)
#pragma unroll
      for (int e2 = 0; e2 < 2; ++e2) {
        asm("v_cvt_pk_bf16_f32 %0, %1, %2"
            : "=v"(pk[0][g][e2]) : "v"(st0[4 * g + 2 * e2]), "v"(st0[4 * g + 2 * e2 + 1]));
        asm("v_cvt_pk_bf16_f32 %0, %1, %2"
            : "=v"(pk[1][g][e2]) : "v"(st1[4 * g + 2 * e2]), "v"(st1[4 * g + 2 * e2 + 1]));
      }
    // redistribute to PV B-frags via v_permlane32_swap (round-2-validated form)
    bf16x8 pf[4];
#pragma unroll
    for (int ks = 0; ks < 4; ++ks) {
      const int jb = ks >> 1, gb = (ks & 1) * 2;
      uintx4 w;
#pragma unroll
      for (int e2 = 0; e2 < 2; ++e2) {
        unsigned d0 = pk[jb][gb][e2], d1 = pk[jb][gb + 1][e2];
        asm("v_permlane32_swap_b32 %0, %1" : "+v"(d0), "+v"(d1));
        w[e2]     = d0;
        w[2 + e2] = d1;
      }
      pf[ks] = *(bf16x8*)&w;
    }

    // PV: O^T[d][i] += V^T[d][j-slice] * P[j-slice][i]
    __builtin_amdgcn_s_setprio(1);
#pragma unroll
    for (int ks = 0; ks < 4; ++ks) {
      accA = __builtin_amdgcn_mfma_f32_32x32x16_bf16(vf0[ks], pf[ks], accA, 0, 0, 0);
      accB = __builtin_amdgcn_mfma_f32_32x32x16_bf16(vf1[ks], pf[ks], accB, 0, 0, 0);
    }
    __builtin_amdgcn_s_setprio(0);

    __syncthreads();  // next K tile staged; all waves done with lK[pr][buf]
    buf ^= 1;
  }

  // ---- in-block KV-split combine (reuse lK as f32 scratch) ----
  // per source wave (2,3): lane slot of 36 f32 (144B, 16B-aligned): U[0..31], m, s
  float* lu = (float*)&lK[0][0][0];
  if (wave >= 2) {
    float* slot = lu + (size_t)(wave - 2) * 2304 + lane * 36;
#pragma unroll
    for (int c = 0; c < 4; ++c) {
      floatx4 t4a = { accA[4 * c], accA[4 * c + 1], accA[4 * c + 2], accA[4 * c + 3] };
      floatx4 t4b = { accB[4 * c], accB[4 * c + 1], accB[4 * c + 2], accB[4 * c + 3] };
      *(floatx4*)(slot + 4 * c) = t4a;
      *(floatx4*)(slot + 16 + 4 * c) = t4b;
    }
    slot[32] = m_;
    slot[33] = s_;
  }
  __syncthreads();
  if (wave < 2) {
    const float* slot = lu + (size_t)wave * 2304 + lane * 36;
    floatx4 u2[8];
#pragma unroll
    for (int c = 0; c < 8; ++c) u2[c] = *(const floatx4*)(slot + 4 * c);
    const float m2 = slot[32], s2 = slot[33];
    const float mm = fmaxf(m_, m2);
    const float a0 = EXP2(m_ - mm), a1 = EXP2(m2 - mm);
    const float invs = 1.0f / (s_ * a0 + s2 * a1);
    const float c0 = a0 * invs, c1 = a1 * invs;

    // epilogue: reg r -> d = db*32 + (r&3) + 8*(r>>2) + 4*hi, col i_
    unsigned short* aor = ao + (size_t)(b * 1024 + i_) * 512 + h * 64 + 4 * hi;
#pragma unroll
    for (int rq = 0; rq < 4; ++rq) {
      float oa0 = accA[4 * rq] * c0 + u2[rq][0] * c1;
      float oa1 = accA[4 * rq + 1] * c0 + u2[rq][1] * c1;
      float oa2 = accA[4 * rq + 2] * c0 + u2[rq][2] * c1;
      float oa3 = accA[4 * rq + 3] * c0 + u2[rq][3] * c1;
      float ob0 = accB[4 * rq] * c0 + u2[4 + rq][0] * c1;
      float ob1 = accB[4 * rq + 1] * c0 + u2[4 + rq][1] * c1;
      float ob2 = accB[4 * rq + 2] * c0 + u2[4 + rq][2] * c1;
      float ob3 = accB[4 * rq + 3] * c0 + u2[4 + rq][3] * c1;
      uint2 u;
      asm("v_cvt_pk_bf16_f32 %0, %1, %2" : "=v"(u.x) : "v"(oa0), "v"(oa1));
      asm("v_cvt_pk_bf16_f32 %0, %1, %2" : "=v"(u.y) : "v"(oa2), "v"(oa3));
      *(uint2*)(aor + 8 * rq) = u;
      asm("v_cvt_pk_bf16_f32 %0, %1, %2" : "=v"(u.x) : "v"(ob0), "v"(ob1));
      asm("v_cvt_pk_bf16_f32 %0, %1, %2" : "=v"(u.y) : "v"(ob2), "v"(ob3));
      *(uint2*)(aor + 32 + 8 * rq) = u;
    }
  }
}

// ================= launch =================
extern "C" void kernel_launch(void* const* d_in, const int* in_sizes, int n_in,
                              void* d_out, int out_size, void* d_ws, size_t ws_size,
                              hipStream_t stream) {
  (void)in_sizes; (void)n_in; (void)out_size; (void)ws_size;
  const float* x      = (const float*)d_in[0];  // [8,1024,512]
  const float* w_qkv  = (const float*)d_in[1];  // [512,1536]
  const float* btab   = (const float*)d_in[2];  // [2047,8]
  const float* w_out  = (const float*)d_in[3];  // [512,512]
  const float* b_out  = (const float*)d_in[4];  // [512]
  float* out = (float*)d_out;

  char* ws = (char*)d_ws;
  unsigned short* xb    = (unsigned short*)(ws);             // 8192*512 bf16
  unsigned short* wqkvT = (unsigned short*)(ws + 8388608);   // [1536][512]
  unsigned short* woutT = (unsigned short*)(ws + 9961472);   // [512][512]
  unsigned short* qb    = (unsigned short*)(ws + 10485760);  // [64][1024][64]
  unsigned short* kb    = (unsigned short*)(ws + 18874368);  // [64][1024][64]
  unsigned short* vT    = (unsigned short*)(ws + 27262976);  // [64][64][1024]
  unsigned short* ao    = (unsigned short*)(ws + 35651584);  // [8192][512]
  float*          btT   = (float*)(ws + 44040192);           // [8][2047] f32

  hipLaunchKernelGGL(cast_f32_bf16, dim3(4096), dim3(256), 0, stream, x, xb, 1048576);
  hipLaunchKernelGGL(tcast_f32_bf16, dim3(3072), dim3(256), 0, stream, w_qkv, wqkvT, 512, 1536);
  hipLaunchKernelGGL(tcast_f32_bf16, dim3(1024), dim3(256), 0, stream, w_out, woutT, 512, 512);
  hipLaunchKernelGGL(tbias_kernel, dim3(64), dim3(256), 0, stream, btab, btT);

  hipLaunchKernelGGL((gemm_bf16<0>), dim3(64, 12), dim3(256), 0, stream,
                     xb, wqkvT, 8192, 1536, 512, qb, kb, vT, (float*)nullptr, (const float*)nullptr);

  hipLaunchKernelGGL(attn_kernel, dim3(1024), dim3(256), 0, stream, qb, kb, vT, btT, ao);

  hipLaunchKernelGGL((gemm_bf16<1>), dim3(64, 4), dim3(256), 0, stream,
                     ao, woutT, 8192, 512, 512,
                     (unsigned short*)nullptr, (unsigned short*)nullptr, (unsigned short*)nullptr,
                     out, b_out);
}

// Round 15
// 100.199 us; speedup vs baseline: 1.2784x; 1.2784x over previous
//
#include <hip/hip_runtime.h>
#include <hip/hip_bf16.h>

// ---- types ----
typedef short bf16x8 __attribute__((ext_vector_type(8)));    // MFMA A/B frag (8 bf16)
typedef float floatx4 __attribute__((ext_vector_type(4)));   // 16x16 MFMA C/D frag
typedef float floatx16 __attribute__((ext_vector_type(16))); // 32x32 MFMA C/D frag
typedef unsigned uintx4 __attribute__((ext_vector_type(4)));

typedef const __attribute__((address_space(1))) void gvoid_t;
typedef __attribute__((address_space(3))) void lvoid_t;

__device__ __forceinline__ void gload_lds16(const void* g, void* l) {
  // wave-uniform LDS base; HW writes 16B at l + lane*16 per lane
  __builtin_amdgcn_global_load_lds((gvoid_t*)g, (lvoid_t*)l, 16, 0, 0);
}

__device__ __forceinline__ unsigned short f2bf(float f) {
  union { float f; unsigned u; } c; c.f = f;
  unsigned u = c.u + 0x7FFFu + ((c.u >> 16) & 1u);  // RNE
  return (unsigned short)(u >> 16);
}

#define LOG2E 1.44269504f
#define EXP2(x) __builtin_amdgcn_exp2f(x)   // raw v_exp_f32 (inputs bounded)

// lane^32 combine on the VALU: v_permlane32_swap swaps vdst[32:63] <-> vsrc[0:31];
// after the swap, {a,b} = {own,partner} pairwise in both halves for commutative
// ops.  The asm v_mov forces b into a distinct register (round-5 lesson:
// same-value "+v","+v" operands got coalesced into a self-swap).
__device__ __forceinline__ float xmax32(float x) {
  float a = x, b;
  asm("v_mov_b32 %0, %1" : "=v"(b) : "v"(x));
  asm("v_permlane32_swap_b32 %0, %1" : "+v"(a), "+v"(b));
  return fmaxf(a, b);
}
__device__ __forceinline__ float xadd32(float x) {
  float a = x, b;
  asm("v_mov_b32 %0, %1" : "=v"(b) : "v"(x));
  asm("v_permlane32_swap_b32 %0, %1" : "+v"(a), "+v"(b));
  return a + b;
}

// ================= fused prep kernel =================
// Four independent jobs in one launch (they used to serialize on the stream):
//   blocks [0,4096):    cast x f32 -> bf16 (float4/ushort4, 1048576 vec4s)
//   blocks [4096,7168): transpose-cast w_qkv [512][1536] -> wqkvT [1536][512]
//   blocks [7168,8192): transpose-cast w_out [512][512]  -> woutT [512][512]
//   blocks [8192,8256): bias table transpose * log2e -> btT [8][2047]
__global__ __launch_bounds__(256) void prep_kernel(
    const float* __restrict__ x,      unsigned short* __restrict__ xb,
    const float* __restrict__ w_qkv,  unsigned short* __restrict__ wqkvT,
    const float* __restrict__ w_out,  unsigned short* __restrict__ woutT,
    const float* __restrict__ btab,   float* __restrict__ btT) {
  const int bid = blockIdx.x;
  if (bid < 4096) {
    int i = bid * 256 + threadIdx.x;            // 1048576 float4s
    float4 v = ((const float4*)x)[i];
    ushort4 o;
    o.x = f2bf(v.x); o.y = f2bf(v.y); o.z = f2bf(v.z); o.w = f2bf(v.w);
    ((ushort4*)xb)[i] = o;
  } else if (bid < 7168) {
    int idx = (bid - 4096) * 256 + threadIdx.x; // 786432 = 512*1536
    int k = idx / 1536, n = idx - k * 1536;
    wqkvT[n * 512 + k] = f2bf(w_qkv[idx]);
  } else if (bid < 8192) {
    int idx = (bid - 7168) * 256 + threadIdx.x; // 262144 = 512*512
    int k = idx >> 9, n = idx & 511;
    woutT[n * 512 + k] = f2bf(w_out[idx]);
  } else {
    int i = (bid - 8192) * 256 + threadIdx.x;
    if (i < 2047 * 8) {
      int idx = i >> 3, hh = i & 7;
      btT[hh * 2047 + idx] = btab[i] * LOG2E;
    }
  }
}

// ================= GEMM: C[m][n] = sum_k A[m][k] * Bt[n][k] =================
// 128x128 tile, BK=64, 4 waves (2x2 of 64x64), mfma 16x16x32 bf16.
// (256,2) + natural block mapping: the (256,3)+swizzle+setprio bundle (r14)
// regressed gemm0+gemm1 by ~20us -- reverted to the r13 proven form.
template <int EPI>
__global__ __launch_bounds__(256, 2) void gemm_bf16(
    const unsigned short* __restrict__ A,   // [M][K] bf16
    const unsigned short* __restrict__ Bt,  // [N][K] bf16
    int M, int N, int K,
    unsigned short* __restrict__ qo, unsigned short* __restrict__ ko,
    unsigned short* __restrict__ vo,
    float* __restrict__ out, const float* __restrict__ bias) {
  __shared__ alignas(16) unsigned short lA[128 * 64];
  __shared__ alignas(16) unsigned short lB[128 * 64];
  const int tid = threadIdx.x;
  const int wave = tid >> 6, lane = tid & 63;
  const int wr = wave >> 1, wc = wave & 1;
  const int lrow = lane & 15, lk = lane >> 4;
  const int m0 = blockIdx.x * 128, n0 = blockIdx.y * 128;

  floatx4 acc[4][4] = {};

  for (int k0 = 0; k0 < K; k0 += 64) {
    __syncthreads();
#pragma unroll
    for (int i = 0; i < 4; ++i) {
      int c = i * 256 + tid;        // chunk id 0..1023 (16B chunks)
      int row = c >> 3, kc = c & 7;
      int ksw = (kc ^ (row & 7)) << 3;  // pre-swizzled source (elements)
      gload_lds16(A + (size_t)(m0 + row) * K + k0 + ksw,
                  &lA[(i * 256 + wave * 64) * 8]);
      gload_lds16(Bt + (size_t)(n0 + row) * K + k0 + ksw,
                  &lB[(i * 256 + wave * 64) * 8]);
    }
    __syncthreads();
#pragma unroll
    for (int f = 0; f < 2; ++f) {
      bf16x8 av[4], bv[4];
      int kc = lk + f * 4;
#pragma unroll
      for (int mt = 0; mt < 4; ++mt) {
        int r = wr * 64 + mt * 16 + lrow;
        av[mt] = *(const bf16x8*)&lA[r * 64 + ((kc ^ (r & 7)) << 3)];
      }
#pragma unroll
      for (int nt = 0; nt < 4; ++nt) {
        int r = wc * 64 + nt * 16 + lrow;
        bv[nt] = *(const bf16x8*)&lB[r * 64 + ((kc ^ (r & 7)) << 3)];
      }
#pragma unroll
      for (int mt = 0; mt < 4; ++mt)
#pragma unroll
        for (int nt = 0; nt < 4; ++nt)
          acc[mt][nt] = __builtin_amdgcn_mfma_f32_16x16x32_bf16(av[mt], bv[nt], acc[mt][nt], 0, 0, 0);
    }
  }

#pragma unroll
  for (int mt = 0; mt < 4; ++mt)
#pragma unroll
    for (int nt = 0; nt < 4; ++nt)
#pragma unroll
      for (int rg = 0; rg < 4; ++rg) {
        int m = m0 + wr * 64 + mt * 16 + lk * 4 + rg;
        int n = n0 + wc * 64 + nt * 16 + lrow;
        float v = acc[mt][nt][rg];
        if constexpr (EPI == 0) {
          int b = m >> 10, ii = m & 1023;
          int sect = n >> 9, r = n & 511;
          int h = r >> 6, d = r & 63;
          size_t bh = (size_t)((b << 3) + h);
          if (sect == 0)      qo[bh * 65536 + (size_t)ii * 64 + d] = f2bf(v * (0.125f * LOG2E));
          else if (sect == 1) ko[bh * 65536 + (size_t)ii * 64 + d] = f2bf(v);
          else                vo[bh * 65536 + (size_t)d * 1024 + ii] = f2bf(v);
        } else {
          out[(size_t)m * N + n] = v + bias[n];
        }
      }
}

// ================= flash attention, 32x32 MFMA, in-block KV-split ===========
// Round-13 proven form (55us): K LDS-staged double-buffer, V direct-early from
// L2, (256,3) no-spill budget, per-lane softmax, permlane P-routing, raw
// v_exp_f32, VALU-only stat exchanges.  No setprio (r14: neutral-to-negative).
__global__ __launch_bounds__(256, 3) void attn_kernel(
    const unsigned short* __restrict__ q,    // [64][1024][64] bf16, pre-scaled 0.125*log2e
    const unsigned short* __restrict__ kbuf, // [64][1024][64] bf16
    const unsigned short* __restrict__ vT,   // [64][64][1024] bf16
    const float* __restrict__ btT,           // [8][2047] f32, pre-scaled log2e
    unsigned short* __restrict__ ao)         // [8][1024][512] bf16
{
  __shared__ alignas(16) unsigned short lK[2][2][64 * 64];  // [pair][dbuf]
  __shared__ float lbias[1088];
  const int tid = threadIdx.x, wave = tid >> 6, lane = tid & 63;
  const int il = lane & 31, hi = lane >> 5;
  const int pr = wave >> 1;                // KV half
  const int wq = wave & 1;                 // q-row half
  // XCD-bijective swizzle: all 16 q-tiles of 8 bh land on one XCD's L2
  const int lid = ((blockIdx.x & 7) << 7) | (blockIdx.x >> 3);
  const int bh = lid >> 4, qt = lid & 15;
  const int h = bh & 7, b = bh >> 3;
  const int qB = qt * 64;
  const int i_ = qB + wq * 32 + il;        // this lane's q-row
  const size_t base = (size_t)bh * 65536;
  const unsigned short* vrow = vT + base;  // [64][1024]

  // stage bias window [qB, qB+1086] -> lbias
  for (int t = tid; t < 1087; t += 256)
    lbias[t] = btT[h * 2047 + qB + t];

  // Q frags (B-operand): Q[i_][kd*16 + hi*8 + e]
  bf16x8 qf[4];
#pragma unroll
  for (int kd = 0; kd < 4; ++kd)
    qf[kd] = *(const bf16x8*)(q + base + (size_t)i_ * 64 + kd * 16 + hi * 8);

  // pair-local staging: 2 waves cover one 64x64 K tile (4 instrs/wave)
#define STAGE_K(dst, jbase)                                                     \
  {                                                                             \
    _Pragma("unroll") for (int i = 0; i < 4; ++i) {                             \
      int c = i * 128 + wq * 64 + lane;                                         \
      int row = c >> 3, kc = c & 7;                                             \
      gload_lds16(kbuf + base + (size_t)((jbase) + row) * 64 + ((kc ^ (row & 7)) << 3), \
                  &(dst)[(i * 128 + wq * 64) * 8]);                             \
    }                                                                           \
  }

  STAGE_K(lK[pr][0], pr * 512);
  __syncthreads();

  floatx16 accA = {}, accB = {};   // O^T[d][i], db = 0 / 1 (unnormalized U)
  float m_ = -1e30f, s_ = 0.f;
  const int bias_off = (i_ - qB) + 1023 - 4 * hi;
  int buf = 0;

  for (int t = 0; t < 8; ++t) {
    const int j0 = pr * 512 + t * 64;
    if (t < 7) STAGE_K(lK[pr][buf ^ 1], j0 + 64);

    // V A-frags direct from global (L2-resident), issued EARLY so the QK^T /
    // softmax phase hides their latency: VT[db*32+il][j0 + ks*16 + hi*8 ..]
    bf16x8 vf0[4], vf1[4];
#pragma unroll
    for (int ks = 0; ks < 4; ++ks) {
      vf0[ks] = *(const bf16x8*)(vrow + (size_t)il * 1024 + j0 + ks * 16 + hi * 8);
      vf1[ks] = *(const bf16x8*)(vrow + (size_t)(32 + il) * 1024 + j0 + ks * 16 + hi * 8);
    }

    // QK^T (swapped): st = mfma(K-frag, Q-frag)
    floatx16 st0 = {}, st1 = {};
#pragma unroll
    for (int kd = 0; kd < 4; ++kd) {
      const int kc = ((kd * 2 + hi) ^ (il & 7)) << 3;
      bf16x8 kf0 = *(const bf16x8*)&lK[pr][buf][il * 64 + kc];
      bf16x8 kf1 = *(const bf16x8*)&lK[pr][buf][(32 + il) * 64 + kc];
      st0 = __builtin_amdgcn_mfma_f32_32x32x16_bf16(kf0, qf[kd], st0, 0, 0, 0);
      st1 = __builtin_amdgcn_mfma_f32_32x32x16_bf16(kf1, qf[kd], st1, 0, 0, 0);
    }

    // + relative bias (LDS); max via 4 independent partial chains
    const int bb = bias_off - j0;
    float pmp[4] = { -1e30f, -1e30f, -1e30f, -1e30f };
#pragma unroll
    for (int r = 0; r < 16; ++r) {
      const int jl = (r & 3) + 8 * (r >> 2);
      st0[r] += lbias[bb - jl];
      st1[r] += lbias[bb - 32 - jl];
      pmp[r & 3] = fmaxf(pmp[r & 3], fmaxf(st0[r], st1[r]));
    }
    float pm = fmaxf(fmaxf(pmp[0], pmp[1]), fmaxf(pmp[2], pmp[3]));
    // full-row max across lane^32 — pure VALU
    pm = xmax32(pm);
    // defer-max (T13): only rescale when max grew by >8 (P bounded by 2^8)
    if (!__all(pm - m_ <= 8.f)) {
      const float nm = fmaxf(m_, pm);
      const float fs = EXP2(m_ - nm);
      s_ *= fs; accA *= fs; accB *= fs;
      m_ = nm;
    }
    // P = exp2(st - m); row-sum via 4 partial accumulators
    float rsp[4] = { 0.f, 0.f, 0.f, 0.f };
#pragma unroll
    for (int r = 0; r < 16; ++r) {
      float e0 = EXP2(st0[r] - m_);
      float e1 = EXP2(st1[r] - m_);
      st0[r] = e0; st1[r] = e1;
      rsp[r & 3] += e0 + e1;
    }
    float rs = (rsp[0] + rsp[1]) + (rsp[2] + rsp[3]);
    s_ += xadd32(rs);   // own + partner halves — pure VALU

    // pack P to bf16 pairs: pk[sb][g][e2] = {lo: bf(st[4g+2e2]), hi: bf(st[4g+2e2+1])}
    unsigned pk[2][4][2];
#pragma unroll
    for (int g = 0; g < 4; ++g)
#pragma unroll
      for (int e2 = 0; e2 < 2; ++e2) {
        asm("v_cvt_pk_bf16_f32 %0, %1, %2"
            : "=v"(pk[0][g][e2]) : "v"(st0[4 * g + 2 * e2]), "v"(st0[4 * g + 2 * e2 + 1]));
        asm("v_cvt_pk_bf16_f32 %0, %1, %2"
            : "=v"(pk[1][g][e2]) : "v"(st1[4 * g + 2 * e2]), "v"(st1[4 * g + 2 * e2 + 1]));
      }
    // redistribute to PV B-frags via v_permlane32_swap (round-2-validated form)
    bf16x8 pf[4];
#pragma unroll
    for (int ks = 0; ks < 4; ++ks) {
      const int jb = ks >> 1, gb = (ks & 1) * 2;
      uintx4 w;
#pragma unroll
      for (int e2 = 0; e2 < 2; ++e2) {
        unsigned d0 = pk[jb][gb][e2], d1 = pk[jb][gb + 1][e2];
        asm("v_permlane32_swap_b32 %0, %1" : "+v"(d0), "+v"(d1));
        w[e2]     = d0;
        w[2 + e2] = d1;
      }
      pf[ks] = *(bf16x8*)&w;
    }

    // PV: O^T[d][i] += V^T[d][j-slice] * P[j-slice][i]
#pragma unroll
    for (int ks = 0; ks < 4; ++ks) {
      accA = __builtin_amdgcn_mfma_f32_32x32x16_bf16(vf0[ks], pf[ks], accA, 0, 0, 0);
      accB = __builtin_amdgcn_mfma_f32_32x32x16_bf16(vf1[ks], pf[ks], accB, 0, 0, 0);
    }

    __syncthreads();  // next K tile staged; all waves done with lK[pr][buf]
    buf ^= 1;
  }

  // ---- in-block KV-split combine (reuse lK as f32 scratch) ----
  // per source wave (2,3): lane slot of 36 f32 (144B, 16B-aligned): U[0..31], m, s
  float* lu = (float*)&lK[0][0][0];
  if (wave >= 2) {
    float* slot = lu + (size_t)(wave - 2) * 2304 + lane * 36;
#pragma unroll
    for (int c = 0; c < 4; ++c) {
      floatx4 t4a = { accA[4 * c], accA[4 * c + 1], accA[4 * c + 2], accA[4 * c + 3] };
      floatx4 t4b = { accB[4 * c], accB[4 * c + 1], accB[4 * c + 2], accB[4 * c + 3] };
      *(floatx4*)(slot + 4 * c) = t4a;
      *(floatx4*)(slot + 16 + 4 * c) = t4b;
    }
    slot[32] = m_;
    slot[33] = s_;
  }
  __syncthreads();
  if (wave < 2) {
    const float* slot = lu + (size_t)wave * 2304 + lane * 36;
    floatx4 u2[8];
#pragma unroll
    for (int c = 0; c < 8; ++c) u2[c] = *(const floatx4*)(slot + 4 * c);
    const float m2 = slot[32], s2 = slot[33];
    const float mm = fmaxf(m_, m2);
    const float a0 = EXP2(m_ - mm), a1 = EXP2(m2 - mm);
    const float invs = 1.0f / (s_ * a0 + s2 * a1);
    const float c0 = a0 * invs, c1 = a1 * invs;

    // epilogue: reg r -> d = db*32 + (r&3) + 8*(r>>2) + 4*hi, col i_
    unsigned short* aor = ao + (size_t)(b * 1024 + i_) * 512 + h * 64 + 4 * hi;
#pragma unroll
    for (int rq = 0; rq < 4; ++rq) {
      float oa0 = accA[4 * rq] * c0 + u2[rq][0] * c1;
      float oa1 = accA[4 * rq + 1] * c0 + u2[rq][1] * c1;
      float oa2 = accA[4 * rq + 2] * c0 + u2[rq][2] * c1;
      float oa3 = accA[4 * rq + 3] * c0 + u2[rq][3] * c1;
      float ob0 = accB[4 * rq] * c0 + u2[4 + rq][0] * c1;
      float ob1 = accB[4 * rq + 1] * c0 + u2[4 + rq][1] * c1;
      float ob2 = accB[4 * rq + 2] * c0 + u2[4 + rq][2] * c1;
      float ob3 = accB[4 * rq + 3] * c0 + u2[4 + rq][3] * c1;
      uint2 u;
      asm("v_cvt_pk_bf16_f32 %0, %1, %2" : "=v"(u.x) : "v"(oa0), "v"(oa1));
      asm("v_cvt_pk_bf16_f32 %0, %1, %2" : "=v"(u.y) : "v"(oa2), "v"(oa3));
      *(uint2*)(aor + 8 * rq) = u;
      asm("v_cvt_pk_bf16_f32 %0, %1, %2" : "=v"(u.x) : "v"(ob0), "v"(ob1));
      asm("v_cvt_pk_bf16_f32 %0, %1, %2" : "=v"(u.y) : "v"(ob2), "v"(ob3));
      *(uint2*)(aor + 32 + 8 * rq) = u;
    }
  }
}

// ================= launch =================
extern "C" void kernel_launch(void* const* d_in, const int* in_sizes, int n_in,
                              void* d_out, int out_size, void* d_ws, size_t ws_size,
                              hipStream_t stream) {
  (void)in_sizes; (void)n_in; (void)out_size; (void)ws_size;
  const float* x      = (const float*)d_in[0];  // [8,1024,512]
  const float* w_qkv  = (const float*)d_in[1];  // [512,1536]
  const float* btab   = (const float*)d_in[2];  // [2047,8]
  const float* w_out  = (const float*)d_in[3];  // [512,512]
  const float* b_out  = (const float*)d_in[4];  // [512]
  float* out = (float*)d_out;

  char* ws = (char*)d_ws;
  unsigned short* xb    = (unsigned short*)(ws);             // 8192*512 bf16
  unsigned short* wqkvT = (unsigned short*)(ws + 8388608);   // [1536][512]
  unsigned short* woutT = (unsigned short*)(ws + 9961472);   // [512][512]
  unsigned short* qb    = (unsigned short*)(ws + 10485760);  // [64][1024][64]
  unsigned short* kb    = (unsigned short*)(ws + 18874368);  // [64][1024][64]
  unsigned short* vT    = (unsigned short*)(ws + 27262976);  // [64][64][1024]
  unsigned short* ao    = (unsigned short*)(ws + 35651584);  // [8192][512]
  float*          btT   = (float*)(ws + 44040192);           // [8][2047] f32

  hipLaunchKernelGGL(prep_kernel, dim3(8256), dim3(256), 0, stream,
                     x, xb, w_qkv, wqkvT, w_out, woutT, btab, btT);

  hipLaunchKernelGGL((gemm_bf16<0>), dim3(64, 12), dim3(256), 0, stream,
                     xb, wqkvT, 8192, 1536, 512, qb, kb, vT, (float*)nullptr, (const float*)nullptr);

  hipLaunchKernelGGL(attn_kernel, dim3(1024), dim3(256), 0, stream, qb, kb, vT, btT, ao);

  hipLaunchKernelGGL((gemm_bf16<1>), dim3(64, 4), dim3(256), 0, stream,
                     ao, woutT, 8192, 512, 512,
                     (unsigned short*)nullptr, (unsigned short*)nullptr, (unsigned short*)nullptr,
                     out, b_out);
}